// Round 21
// baseline (709.378 us; speedup 1.0000x reference)
//
#include <hip/hip_runtime.h>
#include <math.h>

typedef float f32x4 __attribute__((ext_vector_type(4)));
typedef short bf16x8 __attribute__((ext_vector_type(8)));
typedef short bf16x4 __attribute__((ext_vector_type(4)));

__device__ __forceinline__ short f2bf(float f) {
  unsigned u = __builtin_bit_cast(unsigned, f);
  u = (u + 0x7FFFu + ((u >> 16) & 1u)) >> 16;
  return (short)u;
}
__device__ __forceinline__ float bf2f(short s) {
  unsigned u = ((unsigned)(unsigned short)s) << 16;
  return __builtin_bit_cast(float, u);
}
__device__ __forceinline__ float gelu_exact(float x) {
  return 0.5f * x * (1.0f + erff(x * 0.70710678118654752f));
}
// async global->LDS, 16B per lane; lds dest = wave-uniform base + lane*16
__device__ __forceinline__ void gld16(const short* g, short* l) {
  __builtin_amdgcn_global_load_lds(
      (const __attribute__((address_space(1))) void*)g,
      (__attribute__((address_space(3))) void*)l, 16, 0, 0);
}

// window-order row for original pixel row (b, ho, wo): shift by -4 then partition
__device__ __forceinline__ long perm_row(int b, int ho, int wo) {
  int hs = (ho + 252) & 255, ws = (wo + 252) & 255;
  int w = ((hs >> 3) << 5) | (ws >> 3);
  int t = ((hs & 7) << 3) | (ws & 7);
  return ((long)b << 16) | (w << 6) | t;
}

// ---------- LN2: x2 = x(fp32) + yw(bf16 @perm row); outputs x2bf + LN ------
__global__ __launch_bounds__(256) void ln2_kernel(const float* __restrict__ x,
                                                  const short* __restrict__ yw,
                                                  const float* __restrict__ w,
                                                  const float* __restrict__ b,
                                                  short* __restrict__ xn2,
                                                  short* __restrict__ x2bf) {
  int lane = threadIdx.x & 63;
  long row = (long)blockIdx.x * 4 + (threadIdx.x >> 6);
  long drow = perm_row((int)(row >> 16), ((int)row >> 8) & 255, (int)row & 255);
  const float* xr = x + row * 192;
  const short* yr = yw + drow * 192;
  float v0 = xr[lane] + bf2f(yr[lane]);
  float v1 = xr[lane + 64] + bf2f(yr[lane + 64]);
  float v2 = xr[lane + 128] + bf2f(yr[lane + 128]);
  short* xo = x2bf + row * 192;
  xo[lane] = f2bf(v0);
  xo[lane + 64] = f2bf(v1);
  xo[lane + 128] = f2bf(v2);
  float s = v0 + v1 + v2, s2 = v0 * v0 + v1 * v1 + v2 * v2;
#pragma unroll
  for (int m = 1; m < 64; m <<= 1) {
    s += __shfl_xor(s, m);
    s2 += __shfl_xor(s2, m);
  }
  float mu = s * (1.0f / 192.0f);
  float rstd = rsqrtf(s2 * (1.0f / 192.0f) - mu * mu + 1e-5f);
  short* o = xn2 + row * 192;
  o[lane] = f2bf((v0 - mu) * rstd * w[lane] + b[lane]);
  o[lane + 64] = f2bf((v1 - mu) * rstd * w[lane + 64] + b[lane + 64]);
  o[lane + 128] = f2bf((v2 - mu) * rstd * w[lane + 128] + b[lane + 128]);
}

// ---------- weight prep: W[K][N] fp32 -> Bt[N][K] bf16 ----------
__global__ __launch_bounds__(256) void wprep_kernel(const float* __restrict__ w,
                                                    short* __restrict__ bt,
                                                    int K, int N) {
  long i = (long)blockIdx.x * 256 + threadIdx.x;
  if (i >= (long)K * N) return;
  int n = (int)(i / K), k = (int)(i % K);
  bt[i] = f2bf(w[(long)k * N + n]);
}

// ---------- attention bias table: [h][q][k&15][k>>4] (float4-loadable) -----
__global__ __launch_bounds__(256) void bias_prep(const float* __restrict__ rpb,
                                                 float* __restrict__ biasTab) {
  int i = blockIdx.x * 256 + threadIdx.x;  // 6*64*64 = 24576
  int k = i & 63, q = (i >> 6) & 63, h = i >> 12;
  int dr = (q >> 3) - (k >> 3) + 7;
  int dc = (q & 7) - (k & 7) + 7;
  float v = rpb[(dr * 15 + dc) * 6 + h] * 1.4426950408889634f;
  biasTab[(h << 12) + (q << 6) + ((k & 15) << 2) + (k >> 4)] = v;
}

// ---------- FUSED LN1 -> qkv -> attention -> proj, one block per window ----
// r20 proven form + LN1 folded into phase 1: each wave normalizes ~11 of the
// window's 64 tokens straight from x (fp32) into xnt (identical ln1 math).
__global__ __launch_bounds__(384) void fused_attn_kernel(
    const float* __restrict__ x, const float* __restrict__ n1w,
    const float* __restrict__ n1b, const short* __restrict__ bt1,
    const short* __restrict__ bt2, const float* __restrict__ q_b,
    const float* __restrict__ kv_b, const float* __restrict__ proj_b,
    const float* __restrict__ biasTab, short* __restrict__ yw) {
  __shared__ short S_[57344];
  const int tid = threadIdx.x;
  const int lane = tid & 63, wid = tid >> 6;  // wid = head h
  const int lr = lane & 15, lg = lane >> 4;
  const int bid = blockIdx.x;
  const int wglob = (bid & 7) * 256 + (bid >> 3);  // XCD-chunked window id
  const int w = wglob & 1023;
  const int wr = w >> 5, wc = w & 31;
  const long wbase = (long)wglob * 64;
  const int RB = 12800 + wid * 7424;

  // ---- phase 1: inline LN1 for this window's 64 tokens -> xnt (stride 200)
  {
    const int b_ = wglob >> 10;
    const float w0l = n1w[lane], w1l = n1w[lane + 64], w2l = n1w[lane + 128];
    const float b0l = n1b[lane], b1l = n1b[lane + 64], b2l = n1b[lane + 128];
#pragma unroll 1
    for (int t = wid; t < 64; t += 6) {
      int ho = (wr * 8 + (t >> 3) + 4) & 255;
      int wo = (wc * 8 + (t & 7) + 4) & 255;
      const float* xr = x + ((long)(b_ << 16) + (ho << 8) + wo) * 192;
      float v0 = xr[lane], v1 = xr[lane + 64], v2 = xr[lane + 128];
      float s = v0 + v1 + v2, s2 = v0 * v0 + v1 * v1 + v2 * v2;
#pragma unroll
      for (int m = 1; m < 64; m <<= 1) {
        s += __shfl_xor(s, m);
        s2 += __shfl_xor(s2, m);
      }
      float mu = s * (1.0f / 192.0f);
      float rstd = rsqrtf(s2 * (1.0f / 192.0f) - mu * mu + 1e-5f);
      S_[t * 200 + lane] = f2bf((v0 - mu) * rstd * w0l + b0l);
      S_[t * 200 + lane + 64] = f2bf((v1 - mu) * rstd * w1l + b1l);
      S_[t * 200 + lane + 128] = f2bf((v2 - mu) * rstd * w2l + b2l);
    }
  }
  __syncthreads();  // barrier A: xnt ready

  // ---- phase 2: per-head qkv GEMM (cols h*32 of q / k / v) ----
  {
    f32x4 acc[4][6] = {};
#pragma unroll
    for (int ks = 0; ks < 6; ++ks) {
      bf16x8 a[4], b[6];
#pragma unroll
      for (int mf = 0; mf < 4; ++mf)
        a[mf] = *(const bf16x8*)(&S_[(mf * 16 + lr) * 200 + ks * 32 + lg * 8]);
#pragma unroll
      for (int st = 0; st < 3; ++st)
#pragma unroll
        for (int nf = 0; nf < 2; ++nf)
          b[st * 2 + nf] = *(const bf16x8*)(
              bt1 + (long)(st * 192 + wid * 32 + nf * 16 + lr) * 192 +
              ks * 32 + lg * 8);
#pragma unroll
      for (int mf = 0; mf < 4; ++mf)
#pragma unroll
        for (int j = 0; j < 6; ++j)
          acc[mf][j] = __builtin_amdgcn_mfma_f32_16x16x32_bf16(
              a[mf], b[j], acc[mf][j], 0, 0, 0);
    }
#pragma unroll
    for (int mf = 0; mf < 4; ++mf) {
      int row0 = mf * 16 + lg * 4;
#pragma unroll
      for (int nf = 0; nf < 2; ++nf) {
        int c = nf * 16 + lr;
        float qb = q_b[wid * 32 + c];
        float kb = kv_b[wid * 32 + c];
        float vb = kv_b[192 + wid * 32 + c];
#pragma unroll
        for (int r = 0; r < 4; ++r) {
          S_[RB + (row0 + r) * 40 + c] = f2bf(acc[mf][nf][r] + qb);
          S_[RB + 2560 + (row0 + r) * 40 + c] = f2bf(acc[mf][2 + nf][r] + kb);
        }
        bf16x4 vv;
#pragma unroll
        for (int r = 0; r < 4; ++r) vv[r] = f2bf(acc[mf][4 + nf][r] + vb);
        *(bf16x4*)(&S_[RB + 5120 + c * 72 + row0]) = vv;
      }
    }
  }

  // ---- phase 3: QK^T + softmax (no barrier; own region) ----
  bf16x8 aq[4], bk[4];
#pragma unroll
  for (int i = 0; i < 4; ++i) {
    aq[i] = *(const bf16x8*)(&S_[RB + (i * 16 + lr) * 40 + lg * 8]);
    bk[i] = *(const bf16x8*)(&S_[RB + 2560 + (i * 16 + lr) * 40 + lg * 8]);
  }
  f32x4 s[4][4] = {};
#pragma unroll
  for (int mi = 0; mi < 4; ++mi)
#pragma unroll
    for (int ni = 0; ni < 4; ++ni)
      s[mi][ni] = __builtin_amdgcn_mfma_f32_16x16x32_bf16(aq[mi], bk[ni],
                                                          s[mi][ni], 0, 0, 0);

  const float SCL2 = 0.17677669529663687f * 1.4426950408889634f;
  const float MASKC = -144.26950408889634f;
  const bool edge = (wr == 31) || (wc == 31);
  int ridk[4] = {0, 0, 0, 0};
  if (edge) {
#pragma unroll
    for (int ni = 0; ni < 4; ++ni) {
      int k = ni * 16 + lr;
      int kh = wr * 8 + (k >> 3), kw = wc * 8 + (k & 7);
      ridk[ni] = 3 * ((kh < 248) ? 0 : ((kh < 252) ? 1 : 2)) +
                 ((kw < 248) ? 0 : ((kw < 252) ? 1 : 2));
    }
  }
  float rinv[4][4];
#pragma unroll
  for (int mi = 0; mi < 4; ++mi) {
#pragma unroll
    for (int r = 0; r < 4; ++r) {
      int q = mi * 16 + lg * 4 + r;
      // one coalesced float4: bias for k = {lr, lr+16, lr+32, lr+48}
      f32x4 bv4 = *(const f32x4*)(biasTab + (wid << 12) + (q << 6) + (lr << 2));
      int ridq = 0;
      if (edge) {
        int qh = wr * 8 + (q >> 3), qw = wc * 8 + (q & 7);
        ridq = 3 * ((qh < 248) ? 0 : ((qh < 252) ? 1 : 2)) +
               ((qw < 248) ? 0 : ((qw < 252) ? 1 : 2));
      }
      float lv[4];
      float mx = -1e30f;
#pragma unroll
      for (int ni = 0; ni < 4; ++ni) {
        float lvv = s[mi][ni][r] * SCL2 + bv4[ni];
        if (edge && ridq != ridk[ni]) lvv += MASKC;
        lv[ni] = lvv;
        mx = fmaxf(mx, lvv);
      }
#pragma unroll
      for (int m = 1; m < 16; m <<= 1) mx = fmaxf(mx, __shfl_xor(mx, m));
      float sum = 0.0f;
#pragma unroll
      for (int ni = 0; ni < 4; ++ni) {
        float p = exp2f(lv[ni] - mx);
        lv[ni] = p;
        sum += p;
      }
#pragma unroll
      for (int m = 1; m < 16; m <<= 1) sum += __shfl_xor(sum, m);
      rinv[mi][r] = 1.0f / sum;
#pragma unroll
      for (int ni = 0; ni < 4; ++ni)
        S_[RB + q * 72 + ni * 16 + lr] = f2bf(lv[ni]);  // P over Q/K
    }
  }

  // ---- phase 4: O = P @ V (own region; no barrier) ----
  f32x4 o[4][2] = {};
#pragma unroll
  for (int ks = 0; ks < 2; ++ks) {
    bf16x8 ap[4], bv[2];
#pragma unroll
    for (int mi = 0; mi < 4; ++mi)
      ap[mi] = *(const bf16x8*)(&S_[RB + (mi * 16 + lr) * 72 + ks * 32 +
                                    lg * 8]);
#pragma unroll
    for (int ni = 0; ni < 2; ++ni)
      bv[ni] = *(const bf16x8*)(&S_[RB + 5120 + (ni * 16 + lr) * 72 +
                                    ks * 32 + lg * 8]);
#pragma unroll
    for (int mi = 0; mi < 4; ++mi)
#pragma unroll
      for (int ni = 0; ni < 2; ++ni)
        o[mi][ni] = __builtin_amdgcn_mfma_f32_16x16x32_bf16(ap[mi], bv[ni],
                                                            o[mi][ni], 0, 0, 0);
  }
#pragma unroll
  for (int mi = 0; mi < 4; ++mi)
#pragma unroll
    for (int r = 0; r < 4; ++r) {
      int q = mi * 16 + lg * 4 + r;
      float ri = rinv[mi][r];
#pragma unroll
      for (int ni = 0; ni < 2; ++ni)
        S_[RB + q * 40 + ni * 16 + lr] = f2bf(o[mi][ni][r] * ri);
    }
  __syncthreads();  // barrier B: all heads' y slabs ready

  // ---- phase 5: proj -> yw (window order, + bias only; coalesced) ----
  {
    f32x4 acc[4][2] = {};
#pragma unroll
    for (int ks = 0; ks < 6; ++ks) {
      bf16x8 a[4], bq[2];
#pragma unroll
      for (int mf = 0; mf < 4; ++mf)
        a[mf] = *(const bf16x8*)(&S_[12800 + ks * 7424 +
                                     (mf * 16 + lr) * 40 + lg * 8]);
#pragma unroll
      for (int nf = 0; nf < 2; ++nf)
        bq[nf] = *(const bf16x8*)(bt2 +
                                  (long)(wid * 32 + nf * 16 + lr) * 192 +
                                  ks * 32 + lg * 8);
#pragma unroll
      for (int mf = 0; mf < 4; ++mf)
#pragma unroll
        for (int nf = 0; nf < 2; ++nf)
          acc[mf][nf] = __builtin_amdgcn_mfma_f32_16x16x32_bf16(
              a[mf], bq[nf], acc[mf][nf], 0, 0, 0);
    }
#pragma unroll
    for (int mf = 0; mf < 4; ++mf)
#pragma unroll
      for (int nf = 0; nf < 2; ++nf) {
        int n = wid * 32 + nf * 16 + lr;
        float pb = proj_b[n];
#pragma unroll
        for (int r = 0; r < 4; ++r) {
          long m = wbase + mf * 16 + lg * 4 + r;
          yw[m * 192 + n] = f2bf(acc[mf][nf][r] + pb);
        }
      }
  }
}

// ---------- GEMM (K=192): B in regs, gload_lds A (swizzled) — l1 -----------
template <int NTOT, int EPI>
__global__ __launch_bounds__(256) void gemm1_kernel(
    const short* __restrict__ A, const short* __restrict__ Bt,
    const float* __restrict__ B0, short* __restrict__ outp,
    int nblk, int mgx, int iters, int mtiles) {
  __shared__ short As[128 * 192];  // linear tile, XOR-swizzled contents
  const int tid = threadIdx.x;
  const int lane = tid & 63, wid = tid >> 6;
  const int lr = lane & 15, lg = lane >> 4;
  const int xcd = blockIdx.x & 7;
  const int i = blockIdx.x >> 3;
  const int n0 = (i % nblk) * 64;
  const int mg = xcd * mgx + i / nblk;

  bf16x8 bf[6][4];
#pragma unroll
  for (int ks = 0; ks < 6; ++ks)
#pragma unroll
    for (int ni = 0; ni < 4; ++ni)
      bf[ks][ni] = *(const bf16x8*)(Bt + (long)(n0 + ni * 16 + lr) * 192 +
                                    ks * 32 + lg * 8);

  int src_s[12];
#pragma unroll
  for (int s = 0; s < 12; ++s) {
    int lo = (wid * 12 + s) * 1024 + lane * 16;
    int r = lo / 384, c = lo % 384;
    src_s[s] = r * 192 + ((c ^ ((r & 7) << 4)) >> 1);
  }
  const int xorv = (lr & 7) << 4;

#pragma unroll 1
  for (int it = 0; it < iters; ++it) {
    int mt = mg * iters + it;
    if (mt >= mtiles) continue;  // block-uniform
    long m0 = (long)mt * 128;
    const short* Ab = A + m0 * 192;
    __syncthreads();
#pragma unroll
    for (int s = 0; s < 12; ++s)
      gld16(Ab + src_s[s], As + (wid * 12 + s) * 512);
    __syncthreads();
    f32x4 acc[2][4] = {};
#pragma unroll
    for (int ks = 0; ks < 6; ++ks) {
      const char* asb = (const char*)As;
      const int col = (ks * 64 + lg * 16) ^ xorv;
      bf16x8 a0 = *(const bf16x8*)(asb + (wid * 32 + lr) * 384 + col);
      bf16x8 a1 = *(const bf16x8*)(asb + (wid * 32 + 16 + lr) * 384 + col);
#pragma unroll
      for (int ni = 0; ni < 4; ++ni) {
        acc[0][ni] = __builtin_amdgcn_mfma_f32_16x16x32_bf16(a0, bf[ks][ni],
                                                             acc[0][ni], 0, 0, 0);
        acc[1][ni] = __builtin_amdgcn_mfma_f32_16x16x32_bf16(a1, bf[ks][ni],
                                                             acc[1][ni], 0, 0, 0);
      }
    }
#pragma unroll
    for (int mi = 0; mi < 2; ++mi) {
#pragma unroll
      for (int ni = 0; ni < 4; ++ni) {
        int n = n0 + ni * 16 + lr;
        long rowb = m0 + wid * 32 + mi * 16 + lg * 4;
#pragma unroll
        for (int r = 0; r < 4; ++r) {
          long m = rowb + r;
          outp[m * NTOT + n] = f2bf(gelu_exact(acc[mi][ni][r] + B0[n]));
        }
      }
    }
  }
}

// ---------- depthwise 3x3 conv + GELU: 3-row register ring ----------
__global__ __launch_bounds__(256) void dwconv_kernel(const short* __restrict__ hbc,
                                                     const float* __restrict__ dww,
                                                     const float* __restrict__ dwb,
                                                     short* __restrict__ h2c,
                                                     int yh) {
  int t = blockIdx.x * 256 + threadIdx.x;  // over cg*px: 96*256 = 24576
  int cg = t % 96;
  int px = t / 96;
  int strip = blockIdx.y;  // 0..7 -> py = strip*16 .. +15

  float wv[9][8];
#pragma unroll
  for (int tap = 0; tap < 9; ++tap) {
    float4 a = *(const float4*)(dww + tap * 768 + cg * 8);
    float4 b = *(const float4*)(dww + tap * 768 + cg * 8 + 4);
    wv[tap][0] = a.x; wv[tap][1] = a.y; wv[tap][2] = a.z; wv[tap][3] = a.w;
    wv[tap][4] = b.x; wv[tap][5] = b.y; wv[tap][6] = b.z; wv[tap][7] = b.w;
  }
  float bias[8];
  {
    float4 a = *(const float4*)(dwb + cg * 8);
    float4 b = *(const float4*)(dwb + cg * 8 + 4);
    bias[0] = a.x; bias[1] = a.y; bias[2] = a.z; bias[3] = a.w;
    bias[4] = b.x; bias[5] = b.y; bias[6] = b.z; bias[7] = b.w;
  }

  const bool xm = px > 0, xp = px < 255;
  const bf16x8 zz = {};
  bf16x8 rows[3][3];  // [ring slot][dx]; fully-unrolled loop -> static idx

  auto loadrow = [&](int yy, int slot) {
    if (yy < 0 || yy > 255) {
      rows[slot][0] = zz; rows[slot][1] = zz; rows[slot][2] = zz;
    } else {
      const short* base = hbc + ((long)yy * 256 + px) * 768 + cg * 8;
      rows[slot][0] = xm ? *(const bf16x8*)(base - 768) : zz;
      rows[slot][1] = *(const bf16x8*)(base);
      rows[slot][2] = xp ? *(const bf16x8*)(base + 768) : zz;
    }
  };

  const int y0 = yh * 128 + strip * 16;
  loadrow(y0 - 1, 0);
  loadrow(y0, 1);
#pragma unroll
  for (int pp = 0; pp < 16; ++pp) {
    loadrow(y0 + pp + 1, (pp + 2) % 3);
    float acc[8];
#pragma unroll
    for (int j = 0; j < 8; ++j) acc[j] = bias[j];
#pragma unroll
    for (int dy = 0; dy < 3; ++dy) {
      const int slot = (pp + dy) % 3;
#pragma unroll
      for (int dx = 0; dx < 3; ++dx)
#pragma unroll
        for (int j = 0; j < 8; ++j)
          acc[j] += bf2f(rows[slot][dx][j]) * wv[dy * 3 + dx][j];
    }
    bf16x8 ov;
#pragma unroll
    for (int j = 0; j < 8; ++j) ov[j] = f2bf(gelu_exact(acc[j]));
    *(bf16x8*)(h2c + ((long)(strip * 16 + pp) * 256 + px) * 768 + cg * 8) = ov;
  }
}

// ---------- GEMM K=768 (l2): BM=64 x BN=192, grid 512 = 2 blocks/CU --------
__global__ __launch_bounds__(256) void gemm2_kernel(
    const short* __restrict__ A, const short* __restrict__ Bt,
    const float* __restrict__ bias, const short* __restrict__ residb,
    float* __restrict__ outp) {
  __shared__ short As[64][72];   // 9216 B
  __shared__ short Bs[192][72];  // 27648 B
  const int tid = threadIdx.x;
  const int lane = tid & 63, wid = tid >> 6;
  const int lr = lane & 15, lg = lane >> 4;
  const int wm = wid >> 1, wn = wid & 1;
  const int wg = (blockIdx.x & 7) * 64 + (blockIdx.x >> 3);  // XCD swizzle
  const long m0 = (long)wg * 64;

  f32x4 acc[2][6] = {};
#pragma unroll 1
  for (int kc = 0; kc < 12; ++kc) {
    __syncthreads();
#pragma unroll
    for (int p = 0; p < 2; ++p) {
      int g = p * 256 + tid;
      int r = g >> 3, c = g & 7;
      *(float4*)(&As[r][c * 8]) =
          *(const float4*)(A + (m0 + r) * 768 + kc * 64 + c * 8);
    }
#pragma unroll
    for (int p = 0; p < 6; ++p) {
      int g = p * 256 + tid;
      int n = g >> 3, c = g & 7;
      *(float4*)(&Bs[n][c * 8]) =
          *(const float4*)(Bt + (long)n * 768 + kc * 64 + c * 8);
    }
    __syncthreads();
#pragma unroll
    for (int ks = 0; ks < 2; ++ks) {
      bf16x8 a[2], b[6];
#pragma unroll
      for (int mf = 0; mf < 2; ++mf)
        a[mf] = *(const bf16x8*)(&As[wm * 32 + mf * 16 + lr][ks * 32 + lg * 8]);
#pragma unroll
      for (int nf = 0; nf < 6; ++nf)
        b[nf] = *(const bf16x8*)(&Bs[wn * 96 + nf * 16 + lr][ks * 32 + lg * 8]);
#pragma unroll
      for (int mf = 0; mf < 2; ++mf)
#pragma unroll
        for (int nf = 0; nf < 6; ++nf)
          acc[mf][nf] = __builtin_amdgcn_mfma_f32_16x16x32_bf16(
              a[mf], b[nf], acc[mf][nf], 0, 0, 0);
    }
  }
#pragma unroll
  for (int mf = 0; mf < 2; ++mf)
#pragma unroll
    for (int nf = 0; nf < 6; ++nf) {
      int n = wn * 96 + nf * 16 + lr;
      long rowb = m0 + wm * 32 + mf * 16 + lg * 4;
#pragma unroll
      for (int r = 0; r < 4; ++r) {
        long idx = (rowb + r) * 192 + n;
        outp[idx] = acc[mf][nf][r] + bias[n] + bf2f(residb[idx]);
      }
    }
}

// ---------- launch ----------
extern "C" void kernel_launch(void* const* d_in, const int* in_sizes, int n_in,
                              void* d_out, int out_size, void* d_ws, size_t ws_size,
                              hipStream_t stream) {
  const float* x = (const float*)d_in[0];
  const float* n1w = (const float*)d_in[1];
  const float* n1b = (const float*)d_in[2];
  const float* q_w = (const float*)d_in[3];
  const float* q_b = (const float*)d_in[4];
  const float* kv_w = (const float*)d_in[5];
  const float* kv_b = (const float*)d_in[6];
  const float* rpb = (const float*)d_in[7];
  const float* proj_w = (const float*)d_in[8];
  const float* proj_b = (const float*)d_in[9];
  const float* n2w = (const float*)d_in[10];
  const float* n2b = (const float*)d_in[11];
  const float* l1_w = (const float*)d_in[12];
  const float* l1_b = (const float*)d_in[13];
  const float* dw_w = (const float*)d_in[14];
  const float* dw_b = (const float*)d_in[15];
  const float* l2_w = (const float*)d_in[16];
  const float* l2_b = (const float*)d_in[17];
  float* out = (float*)d_out;

  // ---- workspace ----
  char* ws = (char*)d_ws;
  short* xn2 = (short*)ws;                    // [0,48M): LN2 out (token order)
  short* hbc = (short*)(ws + 50331648);       // [48M,144M): 65536*768 bf16
  short* yw = (short*)(ws + 150994944);       // [144M,192M): yw -> h2c
  short* x2bf = (short*)(ws + 201326592);     // [192M,240M) token order bf16
  short* bt1 = (short*)(ws + 251658240);      // [576][192]
  short* bt2 = bt1 + 110592;                  // [192][192]
  short* bt3 = bt2 + 36864;                   // [768][192]
  short* bt4 = bt3 + 147456;                  // [192][768] ends 252,542,976
  float* biasTab = (float*)(ws + 252542976);  // 98,304 B
  short* h2c = yw;

  wprep_kernel<<<144, 256, 0, stream>>>(q_w, bt1, 192, 192);
  wprep_kernel<<<288, 256, 0, stream>>>(kv_w, bt1 + 36864, 192, 384);
  wprep_kernel<<<144, 256, 0, stream>>>(proj_w, bt2, 192, 192);
  wprep_kernel<<<576, 256, 0, stream>>>(l1_w, bt3, 192, 768);
  wprep_kernel<<<576, 256, 0, stream>>>(l2_w, bt4, 768, 192);
  bias_prep<<<96, 256, 0, stream>>>(rpb, biasTab);

  // fused LN1 + qkv + attention + proj (no separate LN1 pass / xn buffer)
  fused_attn_kernel<<<2048, 384, 0, stream>>>(x, n1w, n1b, bt1, bt2, q_b,
                                              kv_b, proj_b, biasTab, yw);
  ln2_kernel<<<32768, 256, 0, stream>>>(x, yw, n2w, n2b, xn2, x2bf);

  // LeFF per batch: full-batch l1 -> hbc; then per y-half: dwconv -> l2
  for (int b = 0; b < 2; ++b) {
    long toff = (long)b * 65536 * 192;
    gemm1_kernel<768, 2><<<1536, 256, 0, stream>>>(
        xn2 + toff, bt3, l1_b, hbc, 12, 16, 4, 512);
    for (int yh = 0; yh < 2; ++yh) {
      long ooff = ((long)b * 65536 + (long)yh * 32768) * 192;
      dwconv_kernel<<<dim3(96, 8), 256, 0, stream>>>(hbc, dw_w, dw_b, h2c, yh);
      gemm2_kernel<<<512, 256, 0, stream>>>(h2c, bt4, l2_b, x2bf + ooff,
                                            out + ooff);
    }
  }
}

// Round 22
// 667.227 us; speedup vs baseline: 1.0632x; 1.0632x over previous
//
#include <hip/hip_runtime.h>
#include <math.h>

typedef float f32x4 __attribute__((ext_vector_type(4)));
typedef short bf16x8 __attribute__((ext_vector_type(8)));
typedef short bf16x4 __attribute__((ext_vector_type(4)));

__device__ __forceinline__ short f2bf(float f) {
  unsigned u = __builtin_bit_cast(unsigned, f);
  u = (u + 0x7FFFu + ((u >> 16) & 1u)) >> 16;
  return (short)u;
}
__device__ __forceinline__ float bf2f(short s) {
  unsigned u = ((unsigned)(unsigned short)s) << 16;
  return __builtin_bit_cast(float, u);
}
__device__ __forceinline__ float gelu_exact(float x) {
  return 0.5f * x * (1.0f + erff(x * 0.70710678118654752f));
}
// async global->LDS, 16B per lane; lds dest = wave-uniform base + lane*16
__device__ __forceinline__ void gld16(const short* g, short* l) {
  __builtin_amdgcn_global_load_lds(
      (const __attribute__((address_space(1))) void*)g,
      (__attribute__((address_space(3))) void*)l, 16, 0, 0);
}

// window-order row for original pixel row (b, ho, wo): shift by -4 then partition
__device__ __forceinline__ long perm_row(int b, int ho, int wo) {
  int hs = (ho + 252) & 255, ws = (wo + 252) & 255;
  int w = ((hs >> 3) << 5) | (ws >> 3);
  int t = ((hs & 7) << 3) | (ws & 7);
  return ((long)b << 16) | (w << 6) | t;
}

// ---------- LN1: fp32 token-order in -> bf16 window-order out ----------
__global__ __launch_bounds__(256) void ln1_kernel(const float* __restrict__ x,
                                                  const float* __restrict__ w,
                                                  const float* __restrict__ b,
                                                  short* __restrict__ out) {
  int lane = threadIdx.x & 63;
  long row = (long)blockIdx.x * 4 + (threadIdx.x >> 6);
  const float* xr = x + row * 192;
  float v0 = xr[lane], v1 = xr[lane + 64], v2 = xr[lane + 128];
  float s = v0 + v1 + v2, s2 = v0 * v0 + v1 * v1 + v2 * v2;
#pragma unroll
  for (int m = 1; m < 64; m <<= 1) {
    s += __shfl_xor(s, m);
    s2 += __shfl_xor(s2, m);
  }
  float mu = s * (1.0f / 192.0f);
  float rstd = rsqrtf(s2 * (1.0f / 192.0f) - mu * mu + 1e-5f);
  long drow = perm_row((int)(row >> 16), ((int)row >> 8) & 255, (int)row & 255);
  short* o = out + drow * 192;
  o[lane] = f2bf((v0 - mu) * rstd * w[lane] + b[lane]);
  o[lane + 64] = f2bf((v1 - mu) * rstd * w[lane + 64] + b[lane + 64]);
  o[lane + 128] = f2bf((v2 - mu) * rstd * w[lane + 128] + b[lane + 128]);
}

// ---------- LN2: x2 = x(fp32) + yw(bf16 @perm row); outputs x2bf + LN ------
__global__ __launch_bounds__(256) void ln2_kernel(const float* __restrict__ x,
                                                  const short* __restrict__ yw,
                                                  const float* __restrict__ w,
                                                  const float* __restrict__ b,
                                                  short* __restrict__ xn2,
                                                  short* __restrict__ x2bf) {
  int lane = threadIdx.x & 63;
  long row = (long)blockIdx.x * 4 + (threadIdx.x >> 6);
  long drow = perm_row((int)(row >> 16), ((int)row >> 8) & 255, (int)row & 255);
  const float* xr = x + row * 192;
  const short* yr = yw + drow * 192;
  float v0 = xr[lane] + bf2f(yr[lane]);
  float v1 = xr[lane + 64] + bf2f(yr[lane + 64]);
  float v2 = xr[lane + 128] + bf2f(yr[lane + 128]);
  short* xo = x2bf + row * 192;
  xo[lane] = f2bf(v0);
  xo[lane + 64] = f2bf(v1);
  xo[lane + 128] = f2bf(v2);
  float s = v0 + v1 + v2, s2 = v0 * v0 + v1 * v1 + v2 * v2;
#pragma unroll
  for (int m = 1; m < 64; m <<= 1) {
    s += __shfl_xor(s, m);
    s2 += __shfl_xor(s2, m);
  }
  float mu = s * (1.0f / 192.0f);
  float rstd = rsqrtf(s2 * (1.0f / 192.0f) - mu * mu + 1e-5f);
  short* o = xn2 + row * 192;
  o[lane] = f2bf((v0 - mu) * rstd * w[lane] + b[lane]);
  o[lane + 64] = f2bf((v1 - mu) * rstd * w[lane + 64] + b[lane + 64]);
  o[lane + 128] = f2bf((v2 - mu) * rstd * w[lane + 128] + b[lane + 128]);
}

// ---------- weight prep: W[K][N] fp32 -> Bt[N][K] bf16 ----------
__global__ __launch_bounds__(256) void wprep_kernel(const float* __restrict__ w,
                                                    short* __restrict__ bt,
                                                    int K, int N) {
  long i = (long)blockIdx.x * 256 + threadIdx.x;
  if (i >= (long)K * N) return;
  int n = (int)(i / K), k = (int)(i % K);
  bt[i] = f2bf(w[(long)k * N + n]);
}

// ---------- attention bias table: [h][q][k&15][k>>4] (float4-loadable) -----
__global__ __launch_bounds__(256) void bias_prep(const float* __restrict__ rpb,
                                                 float* __restrict__ biasTab) {
  int i = blockIdx.x * 256 + threadIdx.x;  // 6*64*64 = 24576
  int k = i & 63, q = (i >> 6) & 63, h = i >> 12;
  int dr = (q >> 3) - (k >> 3) + 7;
  int dc = (q & 7) - (k & 7) + 7;
  float v = rpb[(dr * 15 + dc) * 6 + h] * 1.4426950408889634f;
  biasTab[(h << 12) + (q << 6) + ((k & 15) << 2) + (k >> 4)] = v;
}

// ---------- FUSED qkv -> attention -> proj, one block per window -----------
// r20 proven form. 384 thr = 6 waves, wave h owns head h end-to-end;
// proj writes bias-added y to yw (window order); residual+unperm in LN2.
// Softmax bias: one float4 load per (mi,r).
__global__ __launch_bounds__(384) void fused_attn_kernel(
    const short* __restrict__ xn, const short* __restrict__ bt1,
    const short* __restrict__ bt2, const float* __restrict__ q_b,
    const float* __restrict__ kv_b, const float* __restrict__ proj_b,
    const float* __restrict__ biasTab, short* __restrict__ yw) {
  __shared__ short S_[57344];
  const int tid = threadIdx.x;
  const int lane = tid & 63, wid = tid >> 6;  // wid = head h
  const int lr = lane & 15, lg = lane >> 4;
  const int bid = blockIdx.x;
  const int wglob = (bid & 7) * 256 + (bid >> 3);  // XCD-chunked window id
  const int w = wglob & 1023;
  const int wr = w >> 5, wc = w & 31;
  const long wbase = (long)wglob * 64;
  const int RB = 12800 + wid * 7424;

  // ---- phase 1: stage xn[64][192] -> xnt (stride 200) ----
#pragma unroll
  for (int p = 0; p < 4; ++p) {
    int g = p * 384 + tid;  // 1536 chunks of 16B
    int r = g / 24, c = g % 24;
    *(float4*)(&S_[r * 200 + c * 8]) =
        *(const float4*)(xn + (wbase + r) * 192 + c * 8);
  }
  __syncthreads();  // barrier A

  // ---- phase 2: per-head qkv GEMM (cols h*32 of q / k / v) ----
  {
    f32x4 acc[4][6] = {};
#pragma unroll
    for (int ks = 0; ks < 6; ++ks) {
      bf16x8 a[4], b[6];
#pragma unroll
      for (int mf = 0; mf < 4; ++mf)
        a[mf] = *(const bf16x8*)(&S_[(mf * 16 + lr) * 200 + ks * 32 + lg * 8]);
#pragma unroll
      for (int st = 0; st < 3; ++st)
#pragma unroll
        for (int nf = 0; nf < 2; ++nf)
          b[st * 2 + nf] = *(const bf16x8*)(
              bt1 + (long)(st * 192 + wid * 32 + nf * 16 + lr) * 192 +
              ks * 32 + lg * 8);
#pragma unroll
      for (int mf = 0; mf < 4; ++mf)
#pragma unroll
        for (int j = 0; j < 6; ++j)
          acc[mf][j] = __builtin_amdgcn_mfma_f32_16x16x32_bf16(
              a[mf], b[j], acc[mf][j], 0, 0, 0);
    }
#pragma unroll
    for (int mf = 0; mf < 4; ++mf) {
      int row0 = mf * 16 + lg * 4;
#pragma unroll
      for (int nf = 0; nf < 2; ++nf) {
        int c = nf * 16 + lr;
        float qb = q_b[wid * 32 + c];
        float kb = kv_b[wid * 32 + c];
        float vb = kv_b[192 + wid * 32 + c];
#pragma unroll
        for (int r = 0; r < 4; ++r) {
          S_[RB + (row0 + r) * 40 + c] = f2bf(acc[mf][nf][r] + qb);
          S_[RB + 2560 + (row0 + r) * 40 + c] = f2bf(acc[mf][2 + nf][r] + kb);
        }
        bf16x4 vv;
#pragma unroll
        for (int r = 0; r < 4; ++r) vv[r] = f2bf(acc[mf][4 + nf][r] + vb);
        *(bf16x4*)(&S_[RB + 5120 + c * 72 + row0]) = vv;
      }
    }
  }

  // ---- phase 3: QK^T + softmax (no barrier; own region) ----
  bf16x8 aq[4], bk[4];
#pragma unroll
  for (int i = 0; i < 4; ++i) {
    aq[i] = *(const bf16x8*)(&S_[RB + (i * 16 + lr) * 40 + lg * 8]);
    bk[i] = *(const bf16x8*)(&S_[RB + 2560 + (i * 16 + lr) * 40 + lg * 8]);
  }
  f32x4 s[4][4] = {};
#pragma unroll
  for (int mi = 0; mi < 4; ++mi)
#pragma unroll
    for (int ni = 0; ni < 4; ++ni)
      s[mi][ni] = __builtin_amdgcn_mfma_f32_16x16x32_bf16(aq[mi], bk[ni],
                                                          s[mi][ni], 0, 0, 0);

  const float SCL2 = 0.17677669529663687f * 1.4426950408889634f;
  const float MASKC = -144.26950408889634f;
  const bool edge = (wr == 31) || (wc == 31);
  int ridk[4] = {0, 0, 0, 0};
  if (edge) {
#pragma unroll
    for (int ni = 0; ni < 4; ++ni) {
      int k = ni * 16 + lr;
      int kh = wr * 8 + (k >> 3), kw = wc * 8 + (k & 7);
      ridk[ni] = 3 * ((kh < 248) ? 0 : ((kh < 252) ? 1 : 2)) +
                 ((kw < 248) ? 0 : ((kw < 252) ? 1 : 2));
    }
  }
  float rinv[4][4];
#pragma unroll
  for (int mi = 0; mi < 4; ++mi) {
#pragma unroll
    for (int r = 0; r < 4; ++r) {
      int q = mi * 16 + lg * 4 + r;
      // one coalesced float4: bias for k = {lr, lr+16, lr+32, lr+48}
      f32x4 bv4 = *(const f32x4*)(biasTab + (wid << 12) + (q << 6) + (lr << 2));
      int ridq = 0;
      if (edge) {
        int qh = wr * 8 + (q >> 3), qw = wc * 8 + (q & 7);
        ridq = 3 * ((qh < 248) ? 0 : ((qh < 252) ? 1 : 2)) +
               ((qw < 248) ? 0 : ((qw < 252) ? 1 : 2));
      }
      float lv[4];
      float mx = -1e30f;
#pragma unroll
      for (int ni = 0; ni < 4; ++ni) {
        float lvv = s[mi][ni][r] * SCL2 + bv4[ni];
        if (edge && ridq != ridk[ni]) lvv += MASKC;
        lv[ni] = lvv;
        mx = fmaxf(mx, lvv);
      }
#pragma unroll
      for (int m = 1; m < 16; m <<= 1) mx = fmaxf(mx, __shfl_xor(mx, m));
      float sum = 0.0f;
#pragma unroll
      for (int ni = 0; ni < 4; ++ni) {
        float p = exp2f(lv[ni] - mx);
        lv[ni] = p;
        sum += p;
      }
#pragma unroll
      for (int m = 1; m < 16; m <<= 1) sum += __shfl_xor(sum, m);
      rinv[mi][r] = 1.0f / sum;
#pragma unroll
      for (int ni = 0; ni < 4; ++ni)
        S_[RB + q * 72 + ni * 16 + lr] = f2bf(lv[ni]);  // P over Q/K
    }
  }

  // ---- phase 4: O = P @ V (own region; no barrier) ----
  f32x4 o[4][2] = {};
#pragma unroll
  for (int ks = 0; ks < 2; ++ks) {
    bf16x8 ap[4], bv[2];
#pragma unroll
    for (int mi = 0; mi < 4; ++mi)
      ap[mi] = *(const bf16x8*)(&S_[RB + (mi * 16 + lr) * 72 + ks * 32 +
                                    lg * 8]);
#pragma unroll
    for (int ni = 0; ni < 2; ++ni)
      bv[ni] = *(const bf16x8*)(&S_[RB + 5120 + (ni * 16 + lr) * 72 +
                                    ks * 32 + lg * 8]);
#pragma unroll
    for (int mi = 0; mi < 4; ++mi)
#pragma unroll
      for (int ni = 0; ni < 2; ++ni)
        o[mi][ni] = __builtin_amdgcn_mfma_f32_16x16x32_bf16(ap[mi], bv[ni],
                                                            o[mi][ni], 0, 0, 0);
  }
#pragma unroll
  for (int mi = 0; mi < 4; ++mi)
#pragma unroll
    for (int r = 0; r < 4; ++r) {
      int q = mi * 16 + lg * 4 + r;
      float ri = rinv[mi][r];
#pragma unroll
      for (int ni = 0; ni < 2; ++ni)
        S_[RB + q * 40 + ni * 16 + lr] = f2bf(o[mi][ni][r] * ri);
    }
  __syncthreads();  // barrier B: all heads' y slabs ready

  // ---- phase 5: proj -> yw (window order, + bias only; coalesced) ----
  {
    f32x4 acc[4][2] = {};
#pragma unroll
    for (int ks = 0; ks < 6; ++ks) {
      bf16x8 a[4], bq[2];
#pragma unroll
      for (int mf = 0; mf < 4; ++mf)
        a[mf] = *(const bf16x8*)(&S_[12800 + ks * 7424 +
                                     (mf * 16 + lr) * 40 + lg * 8]);
#pragma unroll
      for (int nf = 0; nf < 2; ++nf)
        bq[nf] = *(const bf16x8*)(bt2 +
                                  (long)(wid * 32 + nf * 16 + lr) * 192 +
                                  ks * 32 + lg * 8);
#pragma unroll
      for (int mf = 0; mf < 4; ++mf)
#pragma unroll
        for (int nf = 0; nf < 2; ++nf)
          acc[mf][nf] = __builtin_amdgcn_mfma_f32_16x16x32_bf16(
              a[mf], bq[nf], acc[mf][nf], 0, 0, 0);
    }
#pragma unroll
    for (int mf = 0; mf < 4; ++mf)
#pragma unroll
      for (int nf = 0; nf < 2; ++nf) {
        int n = wid * 32 + nf * 16 + lr;
        float pb = proj_b[n];
#pragma unroll
        for (int r = 0; r < 4; ++r) {
          long m = wbase + mf * 16 + lg * 4 + r;
          yw[m * 192 + n] = f2bf(acc[mf][nf][r] + pb);
        }
      }
  }
}

// ---------- GEMM (K=192): B in regs, gload_lds A (swizzled) — l1 -----------
template <int NTOT, int EPI>
__global__ __launch_bounds__(256) void gemm1_kernel(
    const short* __restrict__ A, const short* __restrict__ Bt,
    const float* __restrict__ B0, short* __restrict__ outp,
    int nblk, int mgx, int iters, int mtiles) {
  __shared__ short As[128 * 192];  // linear tile, XOR-swizzled contents
  const int tid = threadIdx.x;
  const int lane = tid & 63, wid = tid >> 6;
  const int lr = lane & 15, lg = lane >> 4;
  const int xcd = blockIdx.x & 7;
  const int i = blockIdx.x >> 3;
  const int n0 = (i % nblk) * 64;
  const int mg = xcd * mgx + i / nblk;

  bf16x8 bf[6][4];
#pragma unroll
  for (int ks = 0; ks < 6; ++ks)
#pragma unroll
    for (int ni = 0; ni < 4; ++ni)
      bf[ks][ni] = *(const bf16x8*)(Bt + (long)(n0 + ni * 16 + lr) * 192 +
                                    ks * 32 + lg * 8);

  int src_s[12];
#pragma unroll
  for (int s = 0; s < 12; ++s) {
    int lo = (wid * 12 + s) * 1024 + lane * 16;
    int r = lo / 384, c = lo % 384;
    src_s[s] = r * 192 + ((c ^ ((r & 7) << 4)) >> 1);
  }
  const int xorv = (lr & 7) << 4;

#pragma unroll 1
  for (int it = 0; it < iters; ++it) {
    int mt = mg * iters + it;
    if (mt >= mtiles) continue;  // block-uniform
    long m0 = (long)mt * 128;
    const short* Ab = A + m0 * 192;
    __syncthreads();
#pragma unroll
    for (int s = 0; s < 12; ++s)
      gld16(Ab + src_s[s], As + (wid * 12 + s) * 512);
    __syncthreads();
    f32x4 acc[2][4] = {};
#pragma unroll
    for (int ks = 0; ks < 6; ++ks) {
      const char* asb = (const char*)As;
      const int col = (ks * 64 + lg * 16) ^ xorv;
      bf16x8 a0 = *(const bf16x8*)(asb + (wid * 32 + lr) * 384 + col);
      bf16x8 a1 = *(const bf16x8*)(asb + (wid * 32 + 16 + lr) * 384 + col);
#pragma unroll
      for (int ni = 0; ni < 4; ++ni) {
        acc[0][ni] = __builtin_amdgcn_mfma_f32_16x16x32_bf16(a0, bf[ks][ni],
                                                             acc[0][ni], 0, 0, 0);
        acc[1][ni] = __builtin_amdgcn_mfma_f32_16x16x32_bf16(a1, bf[ks][ni],
                                                             acc[1][ni], 0, 0, 0);
      }
    }
#pragma unroll
    for (int mi = 0; mi < 2; ++mi) {
#pragma unroll
      for (int ni = 0; ni < 4; ++ni) {
        int n = n0 + ni * 16 + lr;
        long rowb = m0 + wid * 32 + mi * 16 + lg * 4;
#pragma unroll
        for (int r = 0; r < 4; ++r) {
          long m = rowb + r;
          outp[m * NTOT + n] = f2bf(gelu_exact(acc[mi][ni][r] + B0[n]));
        }
      }
    }
  }
}

// ---------- depthwise 3x3 conv + GELU: 3-row register ring ----------
__global__ __launch_bounds__(256) void dwconv_kernel(const short* __restrict__ hbc,
                                                     const float* __restrict__ dww,
                                                     const float* __restrict__ dwb,
                                                     short* __restrict__ h2c,
                                                     int yh) {
  int t = blockIdx.x * 256 + threadIdx.x;  // over cg*px: 96*256 = 24576
  int cg = t % 96;
  int px = t / 96;
  int strip = blockIdx.y;  // 0..7 -> py = strip*16 .. +15

  float wv[9][8];
#pragma unroll
  for (int tap = 0; tap < 9; ++tap) {
    float4 a = *(const float4*)(dww + tap * 768 + cg * 8);
    float4 b = *(const float4*)(dww + tap * 768 + cg * 8 + 4);
    wv[tap][0] = a.x; wv[tap][1] = a.y; wv[tap][2] = a.z; wv[tap][3] = a.w;
    wv[tap][4] = b.x; wv[tap][5] = b.y; wv[tap][6] = b.z; wv[tap][7] = b.w;
  }
  float bias[8];
  {
    float4 a = *(const float4*)(dwb + cg * 8);
    float4 b = *(const float4*)(dwb + cg * 8 + 4);
    bias[0] = a.x; bias[1] = a.y; bias[2] = a.z; bias[3] = a.w;
    bias[4] = b.x; bias[5] = b.y; bias[6] = b.z; bias[7] = b.w;
  }

  const bool xm = px > 0, xp = px < 255;
  const bf16x8 zz = {};
  bf16x8 rows[3][3];  // [ring slot][dx]; fully-unrolled loop -> static idx

  auto loadrow = [&](int yy, int slot) {
    if (yy < 0 || yy > 255) {
      rows[slot][0] = zz; rows[slot][1] = zz; rows[slot][2] = zz;
    } else {
      const short* base = hbc + ((long)yy * 256 + px) * 768 + cg * 8;
      rows[slot][0] = xm ? *(const bf16x8*)(base - 768) : zz;
      rows[slot][1] = *(const bf16x8*)(base);
      rows[slot][2] = xp ? *(const bf16x8*)(base + 768) : zz;
    }
  };

  const int y0 = yh * 128 + strip * 16;
  loadrow(y0 - 1, 0);
  loadrow(y0, 1);
#pragma unroll
  for (int pp = 0; pp < 16; ++pp) {
    loadrow(y0 + pp + 1, (pp + 2) % 3);
    float acc[8];
#pragma unroll
    for (int j = 0; j < 8; ++j) acc[j] = bias[j];
#pragma unroll
    for (int dy = 0; dy < 3; ++dy) {
      const int slot = (pp + dy) % 3;
#pragma unroll
      for (int dx = 0; dx < 3; ++dx)
#pragma unroll
        for (int j = 0; j < 8; ++j)
          acc[j] += bf2f(rows[slot][dx][j]) * wv[dy * 3 + dx][j];
    }
    bf16x8 ov;
#pragma unroll
    for (int j = 0; j < 8; ++j) ov[j] = f2bf(gelu_exact(acc[j]));
    *(bf16x8*)(h2c + ((long)(strip * 16 + pp) * 256 + px) * 768 + cg * 8) = ov;
  }
}

// ---------- GEMM K=768 (l2): BM=64 x BN=192, grid 512 = 2 blocks/CU --------
__global__ __launch_bounds__(256) void gemm2_kernel(
    const short* __restrict__ A, const short* __restrict__ Bt,
    const float* __restrict__ bias, const short* __restrict__ residb,
    float* __restrict__ outp) {
  __shared__ short As[64][72];   // 9216 B
  __shared__ short Bs[192][72];  // 27648 B
  const int tid = threadIdx.x;
  const int lane = tid & 63, wid = tid >> 6;
  const int lr = lane & 15, lg = lane >> 4;
  const int wm = wid >> 1, wn = wid & 1;
  const int wg = (blockIdx.x & 7) * 64 + (blockIdx.x >> 3);  // XCD swizzle
  const long m0 = (long)wg * 64;

  f32x4 acc[2][6] = {};
#pragma unroll 1
  for (int kc = 0; kc < 12; ++kc) {
    __syncthreads();
#pragma unroll
    for (int p = 0; p < 2; ++p) {
      int g = p * 256 + tid;
      int r = g >> 3, c = g & 7;
      *(float4*)(&As[r][c * 8]) =
          *(const float4*)(A + (m0 + r) * 768 + kc * 64 + c * 8);
    }
#pragma unroll
    for (int p = 0; p < 6; ++p) {
      int g = p * 256 + tid;
      int n = g >> 3, c = g & 7;
      *(float4*)(&Bs[n][c * 8]) =
          *(const float4*)(Bt + (long)n * 768 + kc * 64 + c * 8);
    }
    __syncthreads();
#pragma unroll
    for (int ks = 0; ks < 2; ++ks) {
      bf16x8 a[2], b[6];
#pragma unroll
      for (int mf = 0; mf < 2; ++mf)
        a[mf] = *(const bf16x8*)(&As[wm * 32 + mf * 16 + lr][ks * 32 + lg * 8]);
#pragma unroll
      for (int nf = 0; nf < 6; ++nf)
        b[nf] = *(const bf16x8*)(&Bs[wn * 96 + nf * 16 + lr][ks * 32 + lg * 8]);
#pragma unroll
      for (int mf = 0; mf < 2; ++mf)
#pragma unroll
        for (int nf = 0; nf < 6; ++nf)
          acc[mf][nf] = __builtin_amdgcn_mfma_f32_16x16x32_bf16(
              a[mf], b[nf], acc[mf][nf], 0, 0, 0);
    }
  }
#pragma unroll
  for (int mf = 0; mf < 2; ++mf)
#pragma unroll
    for (int nf = 0; nf < 6; ++nf) {
      int n = wn * 96 + nf * 16 + lr;
      long rowb = m0 + wm * 32 + mf * 16 + lg * 4;
#pragma unroll
      for (int r = 0; r < 4; ++r) {
        long idx = (rowb + r) * 192 + n;
        outp[idx] = acc[mf][nf][r] + bias[n] + bf2f(residb[idx]);
      }
    }
}

// ---------- launch ----------
extern "C" void kernel_launch(void* const* d_in, const int* in_sizes, int n_in,
                              void* d_out, int out_size, void* d_ws, size_t ws_size,
                              hipStream_t stream) {
  const float* x = (const float*)d_in[0];
  const float* n1w = (const float*)d_in[1];
  const float* n1b = (const float*)d_in[2];
  const float* q_w = (const float*)d_in[3];
  const float* q_b = (const float*)d_in[4];
  const float* kv_w = (const float*)d_in[5];
  const float* kv_b = (const float*)d_in[6];
  const float* rpb = (const float*)d_in[7];
  const float* proj_w = (const float*)d_in[8];
  const float* proj_b = (const float*)d_in[9];
  const float* n2w = (const float*)d_in[10];
  const float* n2b = (const float*)d_in[11];
  const float* l1_w = (const float*)d_in[12];
  const float* l1_b = (const float*)d_in[13];
  const float* dw_w = (const float*)d_in[14];
  const float* dw_b = (const float*)d_in[15];
  const float* l2_w = (const float*)d_in[16];
  const float* l2_b = (const float*)d_in[17];
  float* out = (float*)d_out;

  // ---- workspace ----
  char* ws = (char*)d_ws;
  short* xn = (short*)ws;                     // [0,48M): xn(win) -> xn2
  short* hbc = (short*)(ws + 50331648);       // [48M,144M): 65536*768 bf16
  short* yw = (short*)(ws + 150994944);       // [144M,192M): yw -> h2c
  short* x2bf = (short*)(ws + 201326592);     // [192M,240M) token order bf16
  short* bt1 = (short*)(ws + 251658240);      // [576][192]
  short* bt2 = bt1 + 110592;                  // [192][192]
  short* bt3 = bt2 + 36864;                   // [768][192]
  short* bt4 = bt3 + 147456;                  // [192][768] ends 252,542,976
  float* biasTab = (float*)(ws + 252542976);  // 98,304 B
  short* xn2 = xn;
  short* h2c = yw;

  wprep_kernel<<<144, 256, 0, stream>>>(q_w, bt1, 192, 192);
  wprep_kernel<<<288, 256, 0, stream>>>(kv_w, bt1 + 36864, 192, 384);
  wprep_kernel<<<144, 256, 0, stream>>>(proj_w, bt2, 192, 192);
  wprep_kernel<<<576, 256, 0, stream>>>(l1_w, bt3, 192, 768);
  wprep_kernel<<<576, 256, 0, stream>>>(l2_w, bt4, 768, 192);
  bias_prep<<<96, 256, 0, stream>>>(rpb, biasTab);

  ln1_kernel<<<32768, 256, 0, stream>>>(x, n1w, n1b, xn);
  fused_attn_kernel<<<2048, 384, 0, stream>>>(xn, bt1, bt2, q_b, kv_b, proj_b,
                                              biasTab, yw);
  ln2_kernel<<<32768, 256, 0, stream>>>(x, yw, n2w, n2b, xn2, x2bf);

  // LeFF per batch: full-batch l1 -> hbc; then per y-half: dwconv -> l2
  for (int b = 0; b < 2; ++b) {
    long toff = (long)b * 65536 * 192;
    gemm1_kernel<768, 2><<<1536, 256, 0, stream>>>(
        xn2 + toff, bt3, l1_b, hbc, 12, 16, 4, 512);
    for (int yh = 0; yh < 2; ++yh) {
      long ooff = ((long)b * 65536 + (long)yh * 32768) * 192;
      dwconv_kernel<<<dim3(96, 8), 256, 0, stream>>>(hbc, dw_w, dw_b, h2c, yh);
      gemm2_kernel<<<512, 256, 0, stream>>>(h2c, bt4, l2_b, x2bf + ooff,
                                            out + ooff);
    }
  }
}

// Round 23
// 634.235 us; speedup vs baseline: 1.1185x; 1.0520x over previous
//
#include <hip/hip_runtime.h>
#include <math.h>

typedef float f32x4 __attribute__((ext_vector_type(4)));
typedef short bf16x8 __attribute__((ext_vector_type(8)));
typedef short bf16x4 __attribute__((ext_vector_type(4)));

__device__ __forceinline__ short f2bf(float f) {
  unsigned u = __builtin_bit_cast(unsigned, f);
  u = (u + 0x7FFFu + ((u >> 16) & 1u)) >> 16;
  return (short)u;
}
__device__ __forceinline__ float bf2f(short s) {
  unsigned u = ((unsigned)(unsigned short)s) << 16;
  return __builtin_bit_cast(float, u);
}
// GELU with A&S 7.1.26 erf approximation (|err| < 1.5e-7), hw fast exp.
// ~2x cheaper than libm erff; error << bf16 rounding of these outputs.
__device__ __forceinline__ float gelu_exact(float x) {
  float ax = fabsf(x) * 0.70710678118654752f;
  float t = __frcp_rn(1.0f + 0.3275911f * ax);
  float p = t * (0.254829592f +
            t * (-0.284496736f +
            t * (1.421413741f +
            t * (-1.453152027f + t * 1.061405429f))));
  float er = 1.0f - p * __expf(-ax * ax);
  er = copysignf(er, x);
  return 0.5f * x * (1.0f + er);
}
// async global->LDS, 16B per lane; lds dest = wave-uniform base + lane*16
__device__ __forceinline__ void gld16(const short* g, short* l) {
  __builtin_amdgcn_global_load_lds(
      (const __attribute__((address_space(1))) void*)g,
      (__attribute__((address_space(3))) void*)l, 16, 0, 0);
}

// window-order row for original pixel row (b, ho, wo): shift by -4 then partition
__device__ __forceinline__ long perm_row(int b, int ho, int wo) {
  int hs = (ho + 252) & 255, ws = (wo + 252) & 255;
  int w = ((hs >> 3) << 5) | (ws >> 3);
  int t = ((hs & 7) << 3) | (ws & 7);
  return ((long)b << 16) | (w << 6) | t;
}

// ---------- LN1: fp32 token-order in -> bf16 window-order out ----------
__global__ __launch_bounds__(256) void ln1_kernel(const float* __restrict__ x,
                                                  const float* __restrict__ w,
                                                  const float* __restrict__ b,
                                                  short* __restrict__ out) {
  int lane = threadIdx.x & 63;
  long row = (long)blockIdx.x * 4 + (threadIdx.x >> 6);
  const float* xr = x + row * 192;
  float v0 = xr[lane], v1 = xr[lane + 64], v2 = xr[lane + 128];
  float s = v0 + v1 + v2, s2 = v0 * v0 + v1 * v1 + v2 * v2;
#pragma unroll
  for (int m = 1; m < 64; m <<= 1) {
    s += __shfl_xor(s, m);
    s2 += __shfl_xor(s2, m);
  }
  float mu = s * (1.0f / 192.0f);
  float rstd = rsqrtf(s2 * (1.0f / 192.0f) - mu * mu + 1e-5f);
  long drow = perm_row((int)(row >> 16), ((int)row >> 8) & 255, (int)row & 255);
  short* o = out + drow * 192;
  o[lane] = f2bf((v0 - mu) * rstd * w[lane] + b[lane]);
  o[lane + 64] = f2bf((v1 - mu) * rstd * w[lane + 64] + b[lane + 64]);
  o[lane + 128] = f2bf((v2 - mu) * rstd * w[lane + 128] + b[lane + 128]);
}

// ---------- LN2: x2 = x(fp32) + yw(bf16 @perm row); outputs x2bf + LN ------
__global__ __launch_bounds__(256) void ln2_kernel(const float* __restrict__ x,
                                                  const short* __restrict__ yw,
                                                  const float* __restrict__ w,
                                                  const float* __restrict__ b,
                                                  short* __restrict__ xn2,
                                                  short* __restrict__ x2bf) {
  int lane = threadIdx.x & 63;
  long row = (long)blockIdx.x * 4 + (threadIdx.x >> 6);
  long drow = perm_row((int)(row >> 16), ((int)row >> 8) & 255, (int)row & 255);
  const float* xr = x + row * 192;
  const short* yr = yw + drow * 192;
  float v0 = xr[lane] + bf2f(yr[lane]);
  float v1 = xr[lane + 64] + bf2f(yr[lane + 64]);
  float v2 = xr[lane + 128] + bf2f(yr[lane + 128]);
  short* xo = x2bf + row * 192;
  xo[lane] = f2bf(v0);
  xo[lane + 64] = f2bf(v1);
  xo[lane + 128] = f2bf(v2);
  float s = v0 + v1 + v2, s2 = v0 * v0 + v1 * v1 + v2 * v2;
#pragma unroll
  for (int m = 1; m < 64; m <<= 1) {
    s += __shfl_xor(s, m);
    s2 += __shfl_xor(s2, m);
  }
  float mu = s * (1.0f / 192.0f);
  float rstd = rsqrtf(s2 * (1.0f / 192.0f) - mu * mu + 1e-5f);
  short* o = xn2 + row * 192;
  o[lane] = f2bf((v0 - mu) * rstd * w[lane] + b[lane]);
  o[lane + 64] = f2bf((v1 - mu) * rstd * w[lane + 64] + b[lane + 64]);
  o[lane + 128] = f2bf((v2 - mu) * rstd * w[lane + 128] + b[lane + 128]);
}

// ---------- weight prep: W[K][N] fp32 -> Bt[N][K] bf16 ----------
__global__ __launch_bounds__(256) void wprep_kernel(const float* __restrict__ w,
                                                    short* __restrict__ bt,
                                                    int K, int N) {
  long i = (long)blockIdx.x * 256 + threadIdx.x;
  if (i >= (long)K * N) return;
  int n = (int)(i / K), k = (int)(i % K);
  bt[i] = f2bf(w[(long)k * N + n]);
}

// ---------- attention bias table: [h][q][k&15][k>>4] (float4-loadable) -----
__global__ __launch_bounds__(256) void bias_prep(const float* __restrict__ rpb,
                                                 float* __restrict__ biasTab) {
  int i = blockIdx.x * 256 + threadIdx.x;  // 6*64*64 = 24576
  int k = i & 63, q = (i >> 6) & 63, h = i >> 12;
  int dr = (q >> 3) - (k >> 3) + 7;
  int dc = (q & 7) - (k & 7) + 7;
  float v = rpb[(dr * 15 + dc) * 6 + h] * 1.4426950408889634f;
  biasTab[(h << 12) + (q << 6) + ((k & 15) << 2) + (k >> 4)] = v;
}

// ---------- FUSED qkv -> attention -> proj, one block per window -----------
// r20/r22 proven form. 384 thr = 6 waves, wave h owns head h end-to-end;
// proj writes bias-added y to yw (window order); residual+unperm in LN2.
__global__ __launch_bounds__(384) void fused_attn_kernel(
    const short* __restrict__ xn, const short* __restrict__ bt1,
    const short* __restrict__ bt2, const float* __restrict__ q_b,
    const float* __restrict__ kv_b, const float* __restrict__ proj_b,
    const float* __restrict__ biasTab, short* __restrict__ yw) {
  __shared__ short S_[57344];
  const int tid = threadIdx.x;
  const int lane = tid & 63, wid = tid >> 6;  // wid = head h
  const int lr = lane & 15, lg = lane >> 4;
  const int bid = blockIdx.x;
  const int wglob = (bid & 7) * 256 + (bid >> 3);  // XCD-chunked window id
  const int w = wglob & 1023;
  const int wr = w >> 5, wc = w & 31;
  const long wbase = (long)wglob * 64;
  const int RB = 12800 + wid * 7424;

  // ---- phase 1: stage xn[64][192] -> xnt (stride 200) ----
#pragma unroll
  for (int p = 0; p < 4; ++p) {
    int g = p * 384 + tid;  // 1536 chunks of 16B
    int r = g / 24, c = g % 24;
    *(float4*)(&S_[r * 200 + c * 8]) =
        *(const float4*)(xn + (wbase + r) * 192 + c * 8);
  }
  __syncthreads();  // barrier A

  // ---- phase 2: per-head qkv GEMM (cols h*32 of q / k / v) ----
  {
    f32x4 acc[4][6] = {};
#pragma unroll
    for (int ks = 0; ks < 6; ++ks) {
      bf16x8 a[4], b[6];
#pragma unroll
      for (int mf = 0; mf < 4; ++mf)
        a[mf] = *(const bf16x8*)(&S_[(mf * 16 + lr) * 200 + ks * 32 + lg * 8]);
#pragma unroll
      for (int st = 0; st < 3; ++st)
#pragma unroll
        for (int nf = 0; nf < 2; ++nf)
          b[st * 2 + nf] = *(const bf16x8*)(
              bt1 + (long)(st * 192 + wid * 32 + nf * 16 + lr) * 192 +
              ks * 32 + lg * 8);
#pragma unroll
      for (int mf = 0; mf < 4; ++mf)
#pragma unroll
        for (int j = 0; j < 6; ++j)
          acc[mf][j] = __builtin_amdgcn_mfma_f32_16x16x32_bf16(
              a[mf], b[j], acc[mf][j], 0, 0, 0);
    }
#pragma unroll
    for (int mf = 0; mf < 4; ++mf) {
      int row0 = mf * 16 + lg * 4;
#pragma unroll
      for (int nf = 0; nf < 2; ++nf) {
        int c = nf * 16 + lr;
        float qb = q_b[wid * 32 + c];
        float kb = kv_b[wid * 32 + c];
        float vb = kv_b[192 + wid * 32 + c];
#pragma unroll
        for (int r = 0; r < 4; ++r) {
          S_[RB + (row0 + r) * 40 + c] = f2bf(acc[mf][nf][r] + qb);
          S_[RB + 2560 + (row0 + r) * 40 + c] = f2bf(acc[mf][2 + nf][r] + kb);
        }
        bf16x4 vv;
#pragma unroll
        for (int r = 0; r < 4; ++r) vv[r] = f2bf(acc[mf][4 + nf][r] + vb);
        *(bf16x4*)(&S_[RB + 5120 + c * 72 + row0]) = vv;
      }
    }
  }

  // ---- phase 3: QK^T + softmax (no barrier; own region) ----
  bf16x8 aq[4], bk[4];
#pragma unroll
  for (int i = 0; i < 4; ++i) {
    aq[i] = *(const bf16x8*)(&S_[RB + (i * 16 + lr) * 40 + lg * 8]);
    bk[i] = *(const bf16x8*)(&S_[RB + 2560 + (i * 16 + lr) * 40 + lg * 8]);
  }
  f32x4 s[4][4] = {};
#pragma unroll
  for (int mi = 0; mi < 4; ++mi)
#pragma unroll
    for (int ni = 0; ni < 4; ++ni)
      s[mi][ni] = __builtin_amdgcn_mfma_f32_16x16x32_bf16(aq[mi], bk[ni],
                                                          s[mi][ni], 0, 0, 0);

  const float SCL2 = 0.17677669529663687f * 1.4426950408889634f;
  const float MASKC = -144.26950408889634f;
  const bool edge = (wr == 31) || (wc == 31);
  int ridk[4] = {0, 0, 0, 0};
  if (edge) {
#pragma unroll
    for (int ni = 0; ni < 4; ++ni) {
      int k = ni * 16 + lr;
      int kh = wr * 8 + (k >> 3), kw = wc * 8 + (k & 7);
      ridk[ni] = 3 * ((kh < 248) ? 0 : ((kh < 252) ? 1 : 2)) +
                 ((kw < 248) ? 0 : ((kw < 252) ? 1 : 2));
    }
  }
  float rinv[4][4];
#pragma unroll
  for (int mi = 0; mi < 4; ++mi) {
#pragma unroll
    for (int r = 0; r < 4; ++r) {
      int q = mi * 16 + lg * 4 + r;
      // one coalesced float4: bias for k = {lr, lr+16, lr+32, lr+48}
      f32x4 bv4 = *(const f32x4*)(biasTab + (wid << 12) + (q << 6) + (lr << 2));
      int ridq = 0;
      if (edge) {
        int qh = wr * 8 + (q >> 3), qw = wc * 8 + (q & 7);
        ridq = 3 * ((qh < 248) ? 0 : ((qh < 252) ? 1 : 2)) +
               ((qw < 248) ? 0 : ((qw < 252) ? 1 : 2));
      }
      float lv[4];
      float mx = -1e30f;
#pragma unroll
      for (int ni = 0; ni < 4; ++ni) {
        float lvv = s[mi][ni][r] * SCL2 + bv4[ni];
        if (edge && ridq != ridk[ni]) lvv += MASKC;
        lv[ni] = lvv;
        mx = fmaxf(mx, lvv);
      }
#pragma unroll
      for (int m = 1; m < 16; m <<= 1) mx = fmaxf(mx, __shfl_xor(mx, m));
      float sum = 0.0f;
#pragma unroll
      for (int ni = 0; ni < 4; ++ni) {
        float p = exp2f(lv[ni] - mx);
        lv[ni] = p;
        sum += p;
      }
#pragma unroll
      for (int m = 1; m < 16; m <<= 1) sum += __shfl_xor(sum, m);
      rinv[mi][r] = 1.0f / sum;
#pragma unroll
      for (int ni = 0; ni < 4; ++ni)
        S_[RB + q * 72 + ni * 16 + lr] = f2bf(lv[ni]);  // P over Q/K
    }
  }

  // ---- phase 4: O = P @ V (own region; no barrier) ----
  f32x4 o[4][2] = {};
#pragma unroll
  for (int ks = 0; ks < 2; ++ks) {
    bf16x8 ap[4], bv[2];
#pragma unroll
    for (int mi = 0; mi < 4; ++mi)
      ap[mi] = *(const bf16x8*)(&S_[RB + (mi * 16 + lr) * 72 + ks * 32 +
                                    lg * 8]);
#pragma unroll
    for (int ni = 0; ni < 2; ++ni)
      bv[ni] = *(const bf16x8*)(&S_[RB + 5120 + (ni * 16 + lr) * 72 +
                                    ks * 32 + lg * 8]);
#pragma unroll
    for (int mi = 0; mi < 4; ++mi)
#pragma unroll
      for (int ni = 0; ni < 2; ++ni)
        o[mi][ni] = __builtin_amdgcn_mfma_f32_16x16x32_bf16(ap[mi], bv[ni],
                                                            o[mi][ni], 0, 0, 0);
  }
#pragma unroll
  for (int mi = 0; mi < 4; ++mi)
#pragma unroll
    for (int r = 0; r < 4; ++r) {
      int q = mi * 16 + lg * 4 + r;
      float ri = rinv[mi][r];
#pragma unroll
      for (int ni = 0; ni < 2; ++ni)
        S_[RB + q * 40 + ni * 16 + lr] = f2bf(o[mi][ni][r] * ri);
    }
  __syncthreads();  // barrier B: all heads' y slabs ready

  // ---- phase 5: proj -> yw (window order, + bias only; coalesced) ----
  {
    f32x4 acc[4][2] = {};
#pragma unroll
    for (int ks = 0; ks < 6; ++ks) {
      bf16x8 a[4], bq[2];
#pragma unroll
      for (int mf = 0; mf < 4; ++mf)
        a[mf] = *(const bf16x8*)(&S_[12800 + ks * 7424 +
                                     (mf * 16 + lr) * 40 + lg * 8]);
#pragma unroll
      for (int nf = 0; nf < 2; ++nf)
        bq[nf] = *(const bf16x8*)(bt2 +
                                  (long)(wid * 32 + nf * 16 + lr) * 192 +
                                  ks * 32 + lg * 8);
#pragma unroll
      for (int mf = 0; mf < 4; ++mf)
#pragma unroll
        for (int nf = 0; nf < 2; ++nf)
          acc[mf][nf] = __builtin_amdgcn_mfma_f32_16x16x32_bf16(
              a[mf], bq[nf], acc[mf][nf], 0, 0, 0);
    }
#pragma unroll
    for (int mf = 0; mf < 4; ++mf)
#pragma unroll
      for (int nf = 0; nf < 2; ++nf) {
        int n = wid * 32 + nf * 16 + lr;
        float pb = proj_b[n];
#pragma unroll
        for (int r = 0; r < 4; ++r) {
          long m = wbase + mf * 16 + lg * 4 + r;
          yw[m * 192 + n] = f2bf(acc[mf][nf][r] + pb);
        }
      }
  }
}

// ---------- GEMM (K=192): B in regs, gload_lds A (swizzled) — l1 -----------
template <int NTOT, int EPI>
__global__ __launch_bounds__(256) void gemm1_kernel(
    const short* __restrict__ A, const short* __restrict__ Bt,
    const float* __restrict__ B0, short* __restrict__ outp,
    int nblk, int mgx, int iters, int mtiles) {
  __shared__ short As[128 * 192];  // linear tile, XOR-swizzled contents
  const int tid = threadIdx.x;
  const int lane = tid & 63, wid = tid >> 6;
  const int lr = lane & 15, lg = lane >> 4;
  const int xcd = blockIdx.x & 7;
  const int i = blockIdx.x >> 3;
  const int n0 = (i % nblk) * 64;
  const int mg = xcd * mgx + i / nblk;

  bf16x8 bf[6][4];
#pragma unroll
  for (int ks = 0; ks < 6; ++ks)
#pragma unroll
    for (int ni = 0; ni < 4; ++ni)
      bf[ks][ni] = *(const bf16x8*)(Bt + (long)(n0 + ni * 16 + lr) * 192 +
                                    ks * 32 + lg * 8);

  int src_s[12];
#pragma unroll
  for (int s = 0; s < 12; ++s) {
    int lo = (wid * 12 + s) * 1024 + lane * 16;
    int r = lo / 384, c = lo % 384;
    src_s[s] = r * 192 + ((c ^ ((r & 7) << 4)) >> 1);
  }
  const int xorv = (lr & 7) << 4;

#pragma unroll 1
  for (int it = 0; it < iters; ++it) {
    int mt = mg * iters + it;
    if (mt >= mtiles) continue;  // block-uniform
    long m0 = (long)mt * 128;
    const short* Ab = A + m0 * 192;
    __syncthreads();
#pragma unroll
    for (int s = 0; s < 12; ++s)
      gld16(Ab + src_s[s], As + (wid * 12 + s) * 512);
    __syncthreads();
    f32x4 acc[2][4] = {};
#pragma unroll
    for (int ks = 0; ks < 6; ++ks) {
      const char* asb = (const char*)As;
      const int col = (ks * 64 + lg * 16) ^ xorv;
      bf16x8 a0 = *(const bf16x8*)(asb + (wid * 32 + lr) * 384 + col);
      bf16x8 a1 = *(const bf16x8*)(asb + (wid * 32 + 16 + lr) * 384 + col);
#pragma unroll
      for (int ni = 0; ni < 4; ++ni) {
        acc[0][ni] = __builtin_amdgcn_mfma_f32_16x16x32_bf16(a0, bf[ks][ni],
                                                             acc[0][ni], 0, 0, 0);
        acc[1][ni] = __builtin_amdgcn_mfma_f32_16x16x32_bf16(a1, bf[ks][ni],
                                                             acc[1][ni], 0, 0, 0);
      }
    }
#pragma unroll
    for (int mi = 0; mi < 2; ++mi) {
#pragma unroll
      for (int ni = 0; ni < 4; ++ni) {
        int n = n0 + ni * 16 + lr;
        long rowb = m0 + wid * 32 + mi * 16 + lg * 4;
#pragma unroll
        for (int r = 0; r < 4; ++r) {
          long m = rowb + r;
          outp[m * NTOT + n] = f2bf(gelu_exact(acc[mi][ni][r] + B0[n]));
        }
      }
    }
  }
}

// ---------- depthwise 3x3 conv + GELU: 3-row register ring ----------
__global__ __launch_bounds__(256) void dwconv_kernel(const short* __restrict__ hbc,
                                                     const float* __restrict__ dww,
                                                     const float* __restrict__ dwb,
                                                     short* __restrict__ h2c,
                                                     int yh) {
  int t = blockIdx.x * 256 + threadIdx.x;  // over cg*px: 96*256 = 24576
  int cg = t % 96;
  int px = t / 96;
  int strip = blockIdx.y;  // 0..7 -> py = strip*16 .. +15

  float wv[9][8];
#pragma unroll
  for (int tap = 0; tap < 9; ++tap) {
    float4 a = *(const float4*)(dww + tap * 768 + cg * 8);
    float4 b = *(const float4*)(dww + tap * 768 + cg * 8 + 4);
    wv[tap][0] = a.x; wv[tap][1] = a.y; wv[tap][2] = a.z; wv[tap][3] = a.w;
    wv[tap][4] = b.x; wv[tap][5] = b.y; wv[tap][6] = b.z; wv[tap][7] = b.w;
  }
  float bias[8];
  {
    float4 a = *(const float4*)(dwb + cg * 8);
    float4 b = *(const float4*)(dwb + cg * 8 + 4);
    bias[0] = a.x; bias[1] = a.y; bias[2] = a.z; bias[3] = a.w;
    bias[4] = b.x; bias[5] = b.y; bias[6] = b.z; bias[7] = b.w;
  }

  const bool xm = px > 0, xp = px < 255;
  const bf16x8 zz = {};
  bf16x8 rows[3][3];  // [ring slot][dx]; fully-unrolled loop -> static idx

  auto loadrow = [&](int yy, int slot) {
    if (yy < 0 || yy > 255) {
      rows[slot][0] = zz; rows[slot][1] = zz; rows[slot][2] = zz;
    } else {
      const short* base = hbc + ((long)yy * 256 + px) * 768 + cg * 8;
      rows[slot][0] = xm ? *(const bf16x8*)(base - 768) : zz;
      rows[slot][1] = *(const bf16x8*)(base);
      rows[slot][2] = xp ? *(const bf16x8*)(base + 768) : zz;
    }
  };

  const int y0 = yh * 128 + strip * 16;
  loadrow(y0 - 1, 0);
  loadrow(y0, 1);
#pragma unroll
  for (int pp = 0; pp < 16; ++pp) {
    loadrow(y0 + pp + 1, (pp + 2) % 3);
    float acc[8];
#pragma unroll
    for (int j = 0; j < 8; ++j) acc[j] = bias[j];
#pragma unroll
    for (int dy = 0; dy < 3; ++dy) {
      const int slot = (pp + dy) % 3;
#pragma unroll
      for (int dx = 0; dx < 3; ++dx)
#pragma unroll
        for (int j = 0; j < 8; ++j)
          acc[j] += bf2f(rows[slot][dx][j]) * wv[dy * 3 + dx][j];
    }
    bf16x8 ov;
#pragma unroll
    for (int j = 0; j < 8; ++j) ov[j] = f2bf(gelu_exact(acc[j]));
    *(bf16x8*)(h2c + ((long)(strip * 16 + pp) * 256 + px) * 768 + cg * 8) = ov;
  }
}

// ---------- GEMM K=768 (l2): BM=64 x BN=192, grid 512 = 2 blocks/CU --------
__global__ __launch_bounds__(256) void gemm2_kernel(
    const short* __restrict__ A, const short* __restrict__ Bt,
    const float* __restrict__ bias, const short* __restrict__ residb,
    float* __restrict__ outp) {
  __shared__ short As[64][72];   // 9216 B
  __shared__ short Bs[192][72];  // 27648 B
  const int tid = threadIdx.x;
  const int lane = tid & 63, wid = tid >> 6;
  const int lr = lane & 15, lg = lane >> 4;
  const int wm = wid >> 1, wn = wid & 1;
  const int wg = (blockIdx.x & 7) * 64 + (blockIdx.x >> 3);  // XCD swizzle
  const long m0 = (long)wg * 64;

  f32x4 acc[2][6] = {};
#pragma unroll 1
  for (int kc = 0; kc < 12; ++kc) {
    __syncthreads();
#pragma unroll
    for (int p = 0; p < 2; ++p) {
      int g = p * 256 + tid;
      int r = g >> 3, c = g & 7;
      *(float4*)(&As[r][c * 8]) =
          *(const float4*)(A + (m0 + r) * 768 + kc * 64 + c * 8);
    }
#pragma unroll
    for (int p = 0; p < 6; ++p) {
      int g = p * 256 + tid;
      int n = g >> 3, c = g & 7;
      *(float4*)(&Bs[n][c * 8]) =
          *(const float4*)(Bt + (long)n * 768 + kc * 64 + c * 8);
    }
    __syncthreads();
#pragma unroll
    for (int ks = 0; ks < 2; ++ks) {
      bf16x8 a[2], b[6];
#pragma unroll
      for (int mf = 0; mf < 2; ++mf)
        a[mf] = *(const bf16x8*)(&As[wm * 32 + mf * 16 + lr][ks * 32 + lg * 8]);
#pragma unroll
      for (int nf = 0; nf < 6; ++nf)
        b[nf] = *(const bf16x8*)(&Bs[wn * 96 + nf * 16 + lr][ks * 32 + lg * 8]);
#pragma unroll
      for (int mf = 0; mf < 2; ++mf)
#pragma unroll
        for (int nf = 0; nf < 6; ++nf)
          acc[mf][nf] = __builtin_amdgcn_mfma_f32_16x16x32_bf16(
              a[mf], b[nf], acc[mf][nf], 0, 0, 0);
    }
  }
#pragma unroll
  for (int mf = 0; mf < 2; ++mf)
#pragma unroll
    for (int nf = 0; nf < 6; ++nf) {
      int n = wn * 96 + nf * 16 + lr;
      long rowb = m0 + wm * 32 + mf * 16 + lg * 4;
#pragma unroll
      for (int r = 0; r < 4; ++r) {
        long idx = (rowb + r) * 192 + n;
        outp[idx] = acc[mf][nf][r] + bias[n] + bf2f(residb[idx]);
      }
    }
}

// ---------- launch ----------
extern "C" void kernel_launch(void* const* d_in, const int* in_sizes, int n_in,
                              void* d_out, int out_size, void* d_ws, size_t ws_size,
                              hipStream_t stream) {
  const float* x = (const float*)d_in[0];
  const float* n1w = (const float*)d_in[1];
  const float* n1b = (const float*)d_in[2];
  const float* q_w = (const float*)d_in[3];
  const float* q_b = (const float*)d_in[4];
  const float* kv_w = (const float*)d_in[5];
  const float* kv_b = (const float*)d_in[6];
  const float* rpb = (const float*)d_in[7];
  const float* proj_w = (const float*)d_in[8];
  const float* proj_b = (const float*)d_in[9];
  const float* n2w = (const float*)d_in[10];
  const float* n2b = (const float*)d_in[11];
  const float* l1_w = (const float*)d_in[12];
  const float* l1_b = (const float*)d_in[13];
  const float* dw_w = (const float*)d_in[14];
  const float* dw_b = (const float*)d_in[15];
  const float* l2_w = (const float*)d_in[16];
  const float* l2_b = (const float*)d_in[17];
  float* out = (float*)d_out;

  // ---- workspace ----
  char* ws = (char*)d_ws;
  short* xn = (short*)ws;                     // [0,48M): xn(win) -> xn2
  short* hbc = (short*)(ws + 50331648);       // [48M,144M): 65536*768 bf16
  short* yw = (short*)(ws + 150994944);       // [144M,192M): yw -> h2c
  short* x2bf = (short*)(ws + 201326592);     // [192M,240M) token order bf16
  short* bt1 = (short*)(ws + 251658240);      // [576][192]
  short* bt2 = bt1 + 110592;                  // [192][192]
  short* bt3 = bt2 + 36864;                   // [768][192]
  short* bt4 = bt3 + 147456;                  // [192][768] ends 252,542,976
  float* biasTab = (float*)(ws + 252542976);  // 98,304 B
  short* xn2 = xn;
  short* h2c = yw;

  wprep_kernel<<<144, 256, 0, stream>>>(q_w, bt1, 192, 192);
  wprep_kernel<<<288, 256, 0, stream>>>(kv_w, bt1 + 36864, 192, 384);
  wprep_kernel<<<144, 256, 0, stream>>>(proj_w, bt2, 192, 192);
  wprep_kernel<<<576, 256, 0, stream>>>(l1_w, bt3, 192, 768);
  wprep_kernel<<<576, 256, 0, stream>>>(l2_w, bt4, 768, 192);
  bias_prep<<<96, 256, 0, stream>>>(rpb, biasTab);

  ln1_kernel<<<32768, 256, 0, stream>>>(x, n1w, n1b, xn);
  fused_attn_kernel<<<2048, 384, 0, stream>>>(xn, bt1, bt2, q_b, kv_b, proj_b,
                                              biasTab, yw);
  ln2_kernel<<<32768, 256, 0, stream>>>(x, yw, n2w, n2b, xn2, x2bf);

  // LeFF per batch: full-batch l1 -> hbc; then per y-half: dwconv -> l2
  for (int b = 0; b < 2; ++b) {
    long toff = (long)b * 65536 * 192;
    gemm1_kernel<768, 2><<<1536, 256, 0, stream>>>(
        xn2 + toff, bt3, l1_b, hbc, 12, 16, 4, 512);
    for (int yh = 0; yh < 2; ++yh) {
      long ooff = ((long)b * 65536 + (long)yh * 32768) * 192;
      dwconv_kernel<<<dim3(96, 8), 256, 0, stream>>>(hbc, dw_w, dw_b, h2c, yh);
      gemm2_kernel<<<512, 256, 0, stream>>>(h2c, bt4, l2_b, x2bf + ooff,
                                            out + ooff);
    }
  }
}